// Round 3
// baseline (6131.528 us; speedup 1.0000x reference)
//
#include <hip/hip_runtime.h>
#include <hip/hip_bf16.h>
#include <stdint.h>

// LSTM decoder: H=1024, B=4096, T=128, IN=1.
// R3: 64x128 wave tiles (2-wave / 128-thread blocks) to cut LDS fragment
// read traffic 25% and halve MFMA issue-slot count per FLOP.
// Keeps: global_load_lds w16 staging, XOR-swizzled LDS, XCD-grouped jb.

#define HH 1024
#define BB 4096
#define TT 128

#define BM 128   // batch rows per block
#define BJ 32    // j columns per block (x4 gates = 128 weight rows)
#define BKK 64   // K tile

typedef __bf16 bf16;
typedef __bf16 v8bf __attribute__((ext_vector_type(8)));
typedef float f32x4 __attribute__((ext_vector_type(4)));

__device__ __forceinline__ float fast_sigmoid(float x) {
    return 1.0f / (1.0f + __expf(-x));
}
__device__ __forceinline__ float fast_tanh(float x) {
    return 1.0f - 2.0f / (__expf(2.0f * x) + 1.0f);
}

__device__ __forceinline__ void gload_lds16(const void* g, void* l) {
    __builtin_amdgcn_global_load_lds(
        (const __attribute__((address_space(1))) uint32_t*)(uintptr_t)g,
        (__attribute__((address_space(3))) uint32_t*)(uint32_t)(uintptr_t)l,
        16, 0, 0);
}

// ---- Prologue kernels ------------------------------------------------------

__global__ void prep_weights(const float* __restrict__ Whh,
                             const float* __restrict__ bih,
                             const float* __restrict__ bhh,
                             bf16* __restrict__ Wr,
                             float* __restrict__ bias) {
    int idx = blockIdx.x * blockDim.x + threadIdx.x;
    if (idx < 4 * HH * HH) {
        int k   = idx & (HH - 1);
        int row = idx >> 10;          // Wr row: jb*128 + g*32 + jj
        int jb  = row >> 7;
        int g   = (row >> 5) & 3;
        int jj  = row & 31;
        int srow = g * HH + jb * 32 + jj;
        Wr[idx] = (bf16)Whh[srow * HH + k];
    }
    if (idx < 4 * HH) bias[idx] = bih[idx] + bhh[idx];
}

__global__ void prep_h(const float* __restrict__ h0, bf16* __restrict__ hb) {
    int idx = blockIdx.x * blockDim.x + threadIdx.x;
    if (idx < BB * HH) hb[idx] = (bf16)h0[idx];
}

__global__ void prep_pred(float* __restrict__ predbuf, const float* __restrict__ b_out) {
    int idx = blockIdx.x * blockDim.x + threadIdx.x;
    if (idx < (TT + 1) * BB) predbuf[idx] = (idx < BB) ? 0.0f : b_out[0];
}

// ---- Per-step fused GEMM + cell update ------------------------------------
// 128 threads = 2 waves; wave w computes batch rows [w*64, w*64+64) x all
// 128 weight rows (4 gates x 32 j). acc[mi][nt]: nt>>1 = gate, nt&1 = j-half.

__global__ __launch_bounds__(128, 2)
void lstm_step(const bf16* __restrict__ hread, bf16* __restrict__ hwrite,
               const float* __restrict__ cin, float* __restrict__ cout,
               const bf16* __restrict__ Wr, const float* __restrict__ bias,
               const float* __restrict__ Wih, const float* __restrict__ Wout,
               const float* __restrict__ predbuf_r, float* __restrict__ predbuf_w) {
    // unpadded, XOR-swizzled: physical 16B-chunk = logical_chunk ^ (row & 7)
    __shared__ bf16 As[BM][BKK];   // h tile: batch x k       (16 KB)
    __shared__ bf16 Bs[BM][BKK];   // weights: (4g x 32j) x k (16 KB)

    const int tid  = threadIdx.x;
    const int lane = tid & 63;
    const int w    = tid >> 6;         // wave id 0..1
    const int quad = lane >> 4, l15 = lane & 15;

    const int bid    = blockIdx.x;
    const int jb     = (bid & 7) * 4 + ((bid >> 3) & 3); // 0..31, XCD-grouped
    const int blockB = (bid >> 5) * BM;                  // batch base

    f32x4 acc[4][8]; // [m-tile][n-tile]
#pragma unroll
    for (int mi = 0; mi < 4; mi++)
#pragma unroll
        for (int nt = 0; nt < 8; nt++) acc[mi][nt] = (f32x4){0.f, 0.f, 0.f, 0.f};

    const bf16* Asrc = hread + (size_t)blockB * HH;
    const bf16* Bsrc = Wr + (size_t)jb * 128 * HH;

    const int r8 = lane >> 3;        // 0..7
    const int gc = (lane & 7) ^ r8;  // swizzled global 16B-chunk index
    const int swr = l15 & 7;         // read-side swizzle key (row & 7)

    for (int k0 = 0; k0 < HH; k0 += BKK) {
        // each wave stages 64 rows of A and 64 rows of B: 8 calls each,
        // one call = 64 lanes x 16 B = 8 rows x 128 B
#pragma unroll
        for (int c2 = 0; c2 < 8; c2++) {
            const int rowb = w * 64 + c2 * 8;
            gload_lds16(Asrc + (size_t)(rowb + r8) * HH + k0 + gc * 8, &As[rowb][0]);
            gload_lds16(Bsrc + (size_t)(rowb + r8) * HH + k0 + gc * 8, &Bs[rowb][0]);
        }
        asm volatile("s_waitcnt vmcnt(0)" ::: "memory");
        __syncthreads();
#pragma unroll
        for (int kk = 0; kk < 2; kk++) {
            v8bf a[4], b[8];
            const int pch = ((kk * 4 + quad) ^ swr) * 8;
#pragma unroll
            for (int mi = 0; mi < 4; mi++)
                a[mi] = *(const v8bf*)&As[w * 64 + mi * 16 + l15][pch];
#pragma unroll
            for (int nt = 0; nt < 8; nt++)
                b[nt] = *(const v8bf*)&Bs[nt * 16 + l15][pch];
#pragma unroll
            for (int mi = 0; mi < 4; mi++)
#pragma unroll
                for (int nt = 0; nt < 8; nt++)
                    acc[mi][nt] = __builtin_amdgcn_mfma_f32_16x16x32_bf16(
                        a[mi], b[nt], acc[mi][nt], 0, 0, 0);
        }
        __syncthreads();
    }

    // Epilogue: acc[mi][g*2+jh][r] = gate g at (batch, j):
    //   batch = blockB + w*64 + mi*16 + quad*4 + r
    //   j     = jb*32 + jh*16 + l15
    float wihv[2][4], bsvv[2][4], wov[2];
#pragma unroll
    for (int jh = 0; jh < 2; jh++) {
        const int j = jb * 32 + jh * 16 + l15;
#pragma unroll
        for (int g = 0; g < 4; g++) {
            wihv[jh][g] = Wih[g * HH + j];
            bsvv[jh][g] = bias[g * HH + j];
        }
        wov[jh] = Wout[j];
    }

#pragma unroll
    for (int mi = 0; mi < 4; mi++) {
#pragma unroll
        for (int r = 0; r < 4; r++) {
            const int b = blockB + w * 64 + mi * 16 + quad * 4 + r;
            const float x = predbuf_r[b];  // pred_{t-1} (incl. b_out) or 0 at t=0
            float pacc = 0.0f;
#pragma unroll
            for (int jh = 0; jh < 2; jh++) {
                const int j = jb * 32 + jh * 16 + l15;
                const float gi = acc[mi][0 + jh][r] + x * wihv[jh][0] + bsvv[jh][0];
                const float gf = acc[mi][2 + jh][r] + x * wihv[jh][1] + bsvv[jh][1];
                const float gg = acc[mi][4 + jh][r] + x * wihv[jh][2] + bsvv[jh][2];
                const float go = acc[mi][6 + jh][r] + x * wihv[jh][3] + bsvv[jh][3];
                const float cn = fast_sigmoid(gf) * cin[(size_t)b * HH + j]
                               + fast_sigmoid(gi) * fast_tanh(gg);
                cout[(size_t)b * HH + j] = cn;
                const float hn = fast_sigmoid(go) * fast_tanh(cn);
                hwrite[(size_t)b * HH + j] = (bf16)hn;
                pacc += hn * wov[jh];
            }
            pacc += __shfl_xor(pacc, 1);
            pacc += __shfl_xor(pacc, 2);
            pacc += __shfl_xor(pacc, 4);
            pacc += __shfl_xor(pacc, 8);
            if (l15 == 0) atomicAdd(&predbuf_w[b], pacc);
        }
    }
}

// ---- Output transpose: out[b][t] = pred_t[b] ------------------------------

__global__ void write_out(const float* __restrict__ predbuf, float* __restrict__ out) {
    int idx = blockIdx.x * blockDim.x + threadIdx.x;
    if (idx < BB * TT) {
        int t = idx & (TT - 1);
        int b = idx >> 7;
        out[idx] = predbuf[(size_t)(t + 1) * BB + b];
    }
}

// ---- Host launch -----------------------------------------------------------

extern "C" void kernel_launch(void* const* d_in, const int* in_sizes, int n_in,
                              void* d_out, int out_size, void* d_ws, size_t ws_size,
                              hipStream_t stream) {
    const float* hidden = (const float*)d_in[0];
    const float* cell   = (const float*)d_in[1];
    const float* Wih    = (const float*)d_in[2];
    const float* Whh    = (const float*)d_in[3];
    const float* bih    = (const float*)d_in[4];
    const float* bhh    = (const float*)d_in[5];
    const float* Wout   = (const float*)d_in[6];
    const float* bout   = (const float*)d_in[7];
    float* out = (float*)d_out;

    char* ws = (char*)d_ws;
    bf16* Wr = (bf16*)ws;        ws += (size_t)4 * HH * HH * 2;   // 8 MB
    bf16* hb0 = (bf16*)ws;       ws += (size_t)BB * HH * 2;       // 8 MB
    bf16* hb1 = (bf16*)ws;       ws += (size_t)BB * HH * 2;       // 8 MB
    float* cbuf = (float*)ws;    ws += (size_t)BB * HH * 4;       // 16 MB
    float* bias = (float*)ws;    ws += (size_t)4 * HH * 4;        // 16 KB
    float* predbuf = (float*)ws; ws += (size_t)(TT + 1) * BB * 4; // 2.1 MB

    prep_weights<<<(4 * HH * HH + 255) / 256, 256, 0, stream>>>(Whh, bih, bhh, Wr, bias);
    prep_h<<<(BB * HH + 255) / 256, 256, 0, stream>>>(hidden, hb0);
    prep_pred<<<((TT + 1) * BB + 255) / 256, 256, 0, stream>>>(predbuf, bout);

    bf16* hb[2] = {hb0, hb1};
    for (int t = 0; t < TT; t++) {
        const bf16* hr = hb[t & 1];
        bf16* hw = hb[(t + 1) & 1];
        const float* ci = (t == 0) ? cell : cbuf;
        lstm_step<<<(HH / BJ) * (BB / BM), 128, 0, stream>>>(
            hr, hw, ci, cbuf, Wr, bias, Wih, Wout,
            predbuf + (size_t)t * BB, predbuf + (size_t)(t + 1) * BB);
    }

    write_out<<<(BB * TT + 255) / 256, 256, 0, stream>>>(predbuf, out);
}